// Round 16
// baseline (82.991 us; speedup 1.0000x reference)
//
#include <hip/hip_runtime.h>
#include <float.h>
#include <math.h>

#define Ln 2048
#define Bn 64
#define Cn 512
#define Qn 512
#define Vn 512
#define NO 1536   // C*KW

#define DROW 2064   // padded dpl row: 8 front pad + 2048 + 8 tail pad
#define DPAD 8

// workspace layout (in floats)
#define OFF_DPL  0                                   // dplP[3][B][DROW]= 396288
#define OFF_ABT  396288                              // aBTm[b][t]      = 131072 (masked: a or -1e30)
#define OFF_CST  (OFF_ABT + 131072)                  // cstat[B][8][2]  = 1024
#define OFF_SCR  (OFF_CST + 1024)                    // gpartT[4][3][B][C](393216) / vpart(262144)

typedef float f4 __attribute__((ext_vector_type(4)));
typedef float f2 __attribute__((ext_vector_type(2)));

// ---------------- K1: gpartT[ks][w][b][c] = sum_{k in split ks} q[b,k] W[3c+w,k]  (+bias at ks==0)
__global__ __launch_bounds__(256) void k1_gemm(const float* __restrict__ q,
                                               const float* __restrict__ W,
                                               const float* __restrict__ bias,
                                               float* __restrict__ gpartT) {
    __shared__ __align__(16) float qs[64][68];
    __shared__ __align__(16) float wsm[64][68];
    const int o0 = blockIdx.x * 64;
    const int k0 = blockIdx.y * 128;
    const int tid = threadIdx.x;
    const int ty = tid >> 4, tx = tid & 15;

    f4 accv[4][4];
#pragma unroll
    for (int i = 0; i < 4; ++i)
#pragma unroll
        for (int j = 0; j < 4; ++j) accv[i][j] = (f4)0.f;

    for (int kc = 0; kc < 128; kc += 64) {
#pragma unroll
        for (int r = 0; r < 4; ++r) {
            int idx = tid + r * 256;
            int row = idx >> 4;
            int c4 = (idx & 15) << 2;
            float4 vq = *(const float4*)&q[row * Qn + k0 + kc + c4];
            qs[row][c4 + 0] = vq.x; qs[row][c4 + 1] = vq.y;
            qs[row][c4 + 2] = vq.z; qs[row][c4 + 3] = vq.w;
            float4 vw = *(const float4*)&W[(o0 + row) * Qn + k0 + kc + c4];
            wsm[row][c4 + 0] = vw.x; wsm[row][c4 + 1] = vw.y;
            wsm[row][c4 + 2] = vw.z; wsm[row][c4 + 3] = vw.w;
        }
        __syncthreads();
#pragma unroll
        for (int kk4 = 0; kk4 < 16; ++kk4) {
            f4 qf[4], wf[4];
#pragma unroll
            for (int i = 0; i < 4; ++i) qf[i] = *(const f4*)&qs[ty * 4 + i][kk4 * 4];
#pragma unroll
            for (int j = 0; j < 4; ++j) wf[j] = *(const f4*)&wsm[tx * 4 + j][kk4 * 4];
#pragma unroll
            for (int i = 0; i < 4; ++i)
#pragma unroll
                for (int j = 0; j < 4; ++j) accv[i][j] += qf[i] * wf[j];
        }
        __syncthreads();
    }
    // store transposed: o = 3c + w  ->  gpartT[(ks*3 + w)*Bn*Cn + b*Cn + c]
    const int ks = blockIdx.y;
#pragma unroll
    for (int i = 0; i < 4; ++i) {
        const int b = ty * 4 + i;
#pragma unroll
        for (int j = 0; j < 4; ++j) {
            const int o = o0 + tx * 4 + j;
            const int w = o % 3;
            const int c = o / 3;
            f4 p = accv[i][j];
            float s = (p.x + p.y) + (p.z + p.w);
            if (ks == 0) s += bias[o];
            gpartT[((ks * 3 + w) * Bn + b) * Cn + c] = s;
        }
    }
}

// ---------------- K2: dplP[w][b][8+t] = k[t,b,:]·kern[w][b][:]; wave=(b, 8 t's)
// kern computed in-prologue from gpartT (4 ks-planes summed; bias already folded in).
__global__ __launch_bounds__(256) void k2_dots(const float* __restrict__ kin,
                                               const float* __restrict__ gpartT,
                                               float* __restrict__ dplP) {
    const int wid = (blockIdx.x << 2) + (threadIdx.x >> 6);
    const int lane = threadIdx.x & 63;
    const int b = wid & 63;
    const int t0 = (wid >> 6) << 3;

    f4 kwA[3], kwB[3];
#pragma unroll
    for (int w = 0; w < 3; ++w) {
        f4 sA = (f4)0.f, sB = (f4)0.f;
#pragma unroll
        for (int ks = 0; ks < 4; ++ks) {
            const f4* p = (const f4*)(gpartT + ((ks * 3 + w) * Bn + b) * Cn);
            sA += p[lane];
            sB += p[64 + lane];
        }
        kwA[w] = sA;
        kwB[w] = sB;
    }
#pragma unroll
    for (int ti = 0; ti < 8; ++ti) {
        const int t = t0 + ti;
        const f4* kr = (const f4*)(kin + ((size_t)t * Bn + b) * Cn);
        f4 a = __builtin_nontemporal_load(kr + lane);
        f4 c = __builtin_nontemporal_load(kr + 64 + lane);
        float acc0 = a.x * kwA[0].x + a.y * kwA[0].y + a.z * kwA[0].z + a.w * kwA[0].w
                   + c.x * kwB[0].x + c.y * kwB[0].y + c.z * kwB[0].z + c.w * kwB[0].w;
        float acc1 = a.x * kwA[1].x + a.y * kwA[1].y + a.z * kwA[1].z + a.w * kwA[1].w
                   + c.x * kwB[1].x + c.y * kwB[1].y + c.z * kwB[1].z + c.w * kwB[1].w;
        float acc2 = a.x * kwA[2].x + a.y * kwA[2].y + a.z * kwA[2].z + a.w * kwA[2].w
                   + c.x * kwB[2].x + c.y * kwB[2].y + c.z * kwB[2].z + c.w * kwB[2].w;
#pragma unroll
        for (int off = 32; off; off >>= 1) {
            acc0 += __shfl_xor(acc0, off);
            acc1 += __shfl_xor(acc1, off);
            acc2 += __shfl_xor(acc2, off);
        }
        if (lane == 0) {
            dplP[(0 * Bn + b) * DROW + DPAD + t] = acc0;
            dplP[(1 * Bn + b) * DROW + DPAD + t] = acc1;
            dplP[(2 * Bn + b) * DROW + DPAD + t] = acc2;
        }
    }
}

// ---------------- KA: taps -> out_a (direct scattered) + aBTm (masked, coalesced) + chunk stats
// grid 512 = (c 0..7) x (b 0..63)
__global__ __launch_bounds__(256) void kA_stats(const float* __restrict__ dplP,
                                                const int* __restrict__ kmask,
                                                float* __restrict__ out_a,
                                                float* __restrict__ aBTm,
                                                float* __restrict__ cstat) {
    const int b = blockIdx.x & 63;
    const int c = blockIdx.x >> 6;
    const int tid = threadIdx.x;
    const int t = c * 256 + tid;
    __shared__ float red[4];

    const float* d0 = dplP + (0 * Bn + b) * DROW + DPAD;
    const float* d1 = dplP + (1 * Bn + b) * DROW + DPAD;
    const float* d2 = dplP + (2 * Bn + b) * DROW + DPAD;
    const float x0 = d0[t - 1];
    const float x2 = d2[t + 1];
    const float a = d1[t] + (t > 0 ? x0 : 0.f) + (t < Ln - 1 ? x2 : 0.f);
    const int m = kmask[t * Bn + b];
    out_a[t * Bn + b] = a;                       // direct scattered emit (full occupancy)
    aBTm[b * Ln + t] = m ? a : -1e30f;           // masked value for kB (no kmask read there)

    float lmax = m ? a : -FLT_MAX;
#pragma unroll
    for (int off = 32; off; off >>= 1) lmax = fmaxf(lmax, __shfl_xor(lmax, off));
    if ((tid & 63) == 0) red[tid >> 6] = lmax;
    __syncthreads();
    const float mxc = fmaxf(fmaxf(red[0], red[1]), fmaxf(red[2], red[3]));
    __syncthreads();
    float lsum = m ? __expf(a - mxc) : 0.f;
#pragma unroll
    for (int off = 32; off; off >>= 1) lsum += __shfl_xor(lsum, off);
    if ((tid & 63) == 0) red[tid >> 6] = lsum;
    __syncthreads();
    if (tid == 0) {
        cstat[(b * 8 + c) * 2 + 0] = mxc;
        cstat[(b * 8 + c) * 2 + 1] = red[0] + red[1] + red[2] + red[3];
    }
}

// ---------------- KB: combine stats, e -> out_e (direct), 4-deep significance-sparse PV
// grid 512 = (c 0..7) x (b 0..63)
// PV skips rows with a-mx < -30 (e < 9.4e-14; total attend error < 1e-9 << fp32 noise).
__global__ __launch_bounds__(256) void kB_pv(const float* __restrict__ aBTm,
                                             const float* __restrict__ cstat,
                                             const float* __restrict__ v,
                                             float* __restrict__ out_e,
                                             float* __restrict__ vpart) {
    const int b = blockIdx.x & 63;
    const int c = blockIdx.x >> 6;
    const int tid = threadIdx.x;
    const int t = c * 256 + tid;

    // uniform in-register combine of the 8 chunk stats for this b
    const float* cs = cstat + b * 16;
    float mx = -FLT_MAX;
#pragma unroll
    for (int j = 0; j < 8; ++j)
        if (cs[2 * j + 1] > 0.f) mx = fmaxf(mx, cs[2 * j]);
    float sum = 0.f;
#pragma unroll
    for (int j = 0; j < 8; ++j)
        if (cs[2 * j + 1] > 0.f) sum += cs[2 * j + 1] * __expf(cs[2 * j] - mx);
    const float inv = 1.f / sum;

    const float am = aBTm[b * Ln + t];           // -1e30 where masked -> e == 0
    const float e = __expf(am - mx) * inv;
    out_e[t * Bn + b] = e;                       // direct scattered emit (exact, all t)

    const bool sig = (am - mx) > -30.f;          // significance cutoff for PV only

    __shared__ float es[256];
    __shared__ unsigned long long bm[4];
    __shared__ int lst[256];
    es[tid] = e;
    const unsigned long long bal = __ballot(sig);
    if ((tid & 63) == 0) bm[tid >> 6] = bal;
    __syncthreads();

    // wave-parallel compaction of significant indices into lst (ascending, deterministic)
    const int wv = tid >> 6;
    const int lane = tid & 63;
    int off = 0;
#pragma unroll
    for (int w = 0; w < 4; ++w)
        if (w < wv) off += __popcll(bm[w]);
    if (sig) {
        int rank = __popcll(bal & ((1ull << lane) - 1ull));
        lst[off + rank] = tid;
    }
    const int n = __popcll(bm[0]) + __popcll(bm[1]) + __popcll(bm[2]) + __popcll(bm[3]);
    __syncthreads();

    // 4-deep pipelined sparse PV
    f2 a0 = (f2)0.f, a1 = (f2)0.f, a2 = (f2)0.f, a3 = (f2)0.f;
    int i = 0;
    for (; i + 4 <= n; i += 4) {
        const int t0 = lst[i], t1 = lst[i + 1], t2 = lst[i + 2], t3 = lst[i + 3];
        const f2 v0 = __builtin_nontemporal_load((const f2*)(v + (((size_t)(c * 256 + t0) * Bn + b) << 9)) + tid);
        const f2 v1 = __builtin_nontemporal_load((const f2*)(v + (((size_t)(c * 256 + t1) * Bn + b) << 9)) + tid);
        const f2 v2 = __builtin_nontemporal_load((const f2*)(v + (((size_t)(c * 256 + t2) * Bn + b) << 9)) + tid);
        const f2 v3 = __builtin_nontemporal_load((const f2*)(v + (((size_t)(c * 256 + t3) * Bn + b) << 9)) + tid);
        a0 += es[t0] * v0;
        a1 += es[t1] * v1;
        a2 += es[t2] * v2;
        a3 += es[t3] * v3;
    }
    for (; i < n; ++i) {
        const int tt = lst[i];
        const f2 vv = __builtin_nontemporal_load((const f2*)(v + (((size_t)(c * 256 + tt) * Bn + b) << 9)) + tid);
        a0 += es[tt] * vv;
    }
    const f2 s = (a0 + a1) + (a2 + a3);
    *(f2*)&vpart[((c * Bn + b) << 9) + tid * 2] = s;
}

// ---------------- KC: reduce vpart -> attend[b, v]  (128 blocks)
__global__ __launch_bounds__(256) void kC_fin(const float* __restrict__ vpart,
                                              float* __restrict__ out_att) {
    const int idx = blockIdx.x * 256 + threadIdx.x;   // [0, 32768)
    float s = 0.f;
#pragma unroll
    for (int cc = 0; cc < 8; ++cc) s += vpart[cc * (Bn * Vn) + idx];
    out_att[idx] = s;
}

extern "C" void kernel_launch(void* const* d_in, const int* in_sizes, int n_in,
                              void* d_out, int out_size, void* d_ws, size_t ws_size,
                              hipStream_t stream) {
    const float* q = (const float*)d_in[0];
    const float* k = (const float*)d_in[1];
    const float* v = (const float*)d_in[2];
    const int* kmask = (const int*)d_in[3];
    const float* W = (const float*)d_in[4];
    const float* bias = (const float*)d_in[5];

    float* out = (float*)d_out;
    float* out_a = out;                      // [L, B]
    float* out_e = out + Ln * Bn;            // [L, B]
    float* out_att = out + 2 * Ln * Bn;      // [B, V]

    float* ws = (float*)d_ws;
    float* dplP = ws + OFF_DPL;
    float* aBTm = ws + OFF_ABT;
    float* cstat = ws + OFF_CST;
    float* scr = ws + OFF_SCR;   // gpartT (k1->k2 phase) then vpart (kB->kC phase) — disjoint in time

    k1_gemm<<<dim3(24, 4), 256, 0, stream>>>(q, W, bias, scr);
    k2_dots<<<4096, 256, 0, stream>>>(k, scr, dplP);
    kA_stats<<<512, 256, 0, stream>>>(dplP, kmask, out_a, aBTm, cstat);
    kB_pv<<<512, 256, 0, stream>>>(aBTm, cstat, v, out_e, scr);
    kC_fin<<<128, 256, 0, stream>>>(scr, out_att);
}

// Round 17
// 72.327 us; speedup vs baseline: 1.1474x; 1.1474x over previous
//
#include <hip/hip_runtime.h>
#include <float.h>
#include <math.h>

#define Ln 2048
#define Bn 64
#define Cn 512
#define Qn 512
#define Vn 512
#define NO 1536   // C*KW

#define DROW 2064   // padded dpl row: 8 front pad + 2048 + 8 tail pad
#define DPAD 8

// workspace layout (in floats)
#define OFF_KERN 0                                   // kern[3][B][C]   = 98304
#define OFF_DPL  98304                               // dplP[3][B][DROW]= 396288
#define OFF_ABT  (OFF_DPL + 396288)                  // aBTm[b][t]      = 131072 (masked: a or -1e30)
#define OFF_CST  (OFF_ABT + 131072)                  // cstat[B][8][2]  = 1024
#define OFF_SCR  (OFF_CST + 1024)                    // gpart(393216) / vpart(262144)

typedef float f4 __attribute__((ext_vector_type(4)));
typedef float f2 __attribute__((ext_vector_type(2)));

// ---------------- K1: gpart[ks][b][o] = sum_{k in split} q[b,k] W[o,k]
__global__ __launch_bounds__(256) void k1_gemm(const float* __restrict__ q,
                                               const float* __restrict__ W,
                                               float* __restrict__ gpart) {
    __shared__ __align__(16) float qs[64][68];
    __shared__ __align__(16) float wsm[64][68];
    const int o0 = blockIdx.x * 64;
    const int k0 = blockIdx.y * 128;
    const int tid = threadIdx.x;
    const int ty = tid >> 4, tx = tid & 15;

    f4 accv[4][4];
#pragma unroll
    for (int i = 0; i < 4; ++i)
#pragma unroll
        for (int j = 0; j < 4; ++j) accv[i][j] = (f4)0.f;

    for (int kc = 0; kc < 128; kc += 64) {
#pragma unroll
        for (int r = 0; r < 4; ++r) {
            int idx = tid + r * 256;
            int row = idx >> 4;
            int c4 = (idx & 15) << 2;
            float4 vq = *(const float4*)&q[row * Qn + k0 + kc + c4];
            qs[row][c4 + 0] = vq.x; qs[row][c4 + 1] = vq.y;
            qs[row][c4 + 2] = vq.z; qs[row][c4 + 3] = vq.w;
            float4 vw = *(const float4*)&W[(o0 + row) * Qn + k0 + kc + c4];
            wsm[row][c4 + 0] = vw.x; wsm[row][c4 + 1] = vw.y;
            wsm[row][c4 + 2] = vw.z; wsm[row][c4 + 3] = vw.w;
        }
        __syncthreads();
#pragma unroll
        for (int kk4 = 0; kk4 < 16; ++kk4) {
            f4 qf[4], wf[4];
#pragma unroll
            for (int i = 0; i < 4; ++i) qf[i] = *(const f4*)&qs[ty * 4 + i][kk4 * 4];
#pragma unroll
            for (int j = 0; j < 4; ++j) wf[j] = *(const f4*)&wsm[tx * 4 + j][kk4 * 4];
#pragma unroll
            for (int i = 0; i < 4; ++i)
#pragma unroll
                for (int j = 0; j < 4; ++j) accv[i][j] += qf[i] * wf[j];
        }
        __syncthreads();
    }
#pragma unroll
    for (int i = 0; i < 4; ++i) {
        float4 w4;
        f4 p;
        p = accv[i][0]; w4.x = (p.x + p.y) + (p.z + p.w);
        p = accv[i][1]; w4.y = (p.x + p.y) + (p.z + p.w);
        p = accv[i][2]; w4.z = (p.x + p.y) + (p.z + p.w);
        p = accv[i][3]; w4.w = (p.x + p.y) + (p.z + p.w);
        *(float4*)&gpart[(blockIdx.y * 64 + ty * 4 + i) * NO + o0 + tx * 4] = w4;
    }
}

// ---------------- K1b: reduce k-splits + bias, transpose to kern[w][b][c]
__global__ __launch_bounds__(256) void k1b_reduce(const float* __restrict__ gpart,
                                                  const float* __restrict__ bias,
                                                  float* __restrict__ kern) {
    int idx = blockIdx.x * 256 + threadIdx.x;
    if (idx >= 3 * Bn * Cn) return;
    int w = idx / (Bn * Cn);
    int rem = idx - w * (Bn * Cn);
    int b = rem >> 9;
    int c = rem & 511;
    int o = c * 3 + w;
    float s = bias[o];
#pragma unroll
    for (int ks = 0; ks < 4; ++ks) s += gpart[(ks * Bn + b) * NO + o];
    kern[idx] = s;
}

// ---------------- K2 (R2/R5 variant): dplP[w][b][8+t] = k[t,b,:]·kern[w][b][:]; wave=(b, 8 t's)
__global__ __launch_bounds__(256) void k2_dots(const float* __restrict__ kin,
                                               const float* __restrict__ kern,
                                               float* __restrict__ dplP) {
    const int wid = (blockIdx.x << 2) + (threadIdx.x >> 6);
    const int lane = threadIdx.x & 63;
    const int b = wid & 63;
    const int t0 = (wid >> 6) << 3;

    f4 kwA[3], kwB[3];
#pragma unroll
    for (int w = 0; w < 3; ++w) {
        const f4* p = (const f4*)(kern + (w * Bn + b) * Cn);
        kwA[w] = p[lane];
        kwB[w] = p[64 + lane];
    }
#pragma unroll
    for (int ti = 0; ti < 8; ++ti) {
        const int t = t0 + ti;
        const f4* kr = (const f4*)(kin + ((size_t)t * Bn + b) * Cn);
        f4 a = __builtin_nontemporal_load(kr + lane);
        f4 c = __builtin_nontemporal_load(kr + 64 + lane);
        float acc0 = a.x * kwA[0].x + a.y * kwA[0].y + a.z * kwA[0].z + a.w * kwA[0].w
                   + c.x * kwB[0].x + c.y * kwB[0].y + c.z * kwB[0].z + c.w * kwB[0].w;
        float acc1 = a.x * kwA[1].x + a.y * kwA[1].y + a.z * kwA[1].z + a.w * kwA[1].w
                   + c.x * kwB[1].x + c.y * kwB[1].y + c.z * kwB[1].z + c.w * kwB[1].w;
        float acc2 = a.x * kwA[2].x + a.y * kwA[2].y + a.z * kwA[2].z + a.w * kwA[2].w
                   + c.x * kwB[2].x + c.y * kwB[2].y + c.z * kwB[2].z + c.w * kwB[2].w;
#pragma unroll
        for (int off = 32; off; off >>= 1) {
            acc0 += __shfl_xor(acc0, off);
            acc1 += __shfl_xor(acc1, off);
            acc2 += __shfl_xor(acc2, off);
        }
        if (lane == 0) {
            dplP[(0 * Bn + b) * DROW + DPAD + t] = acc0;
            dplP[(1 * Bn + b) * DROW + DPAD + t] = acc1;
            dplP[(2 * Bn + b) * DROW + DPAD + t] = acc2;
        }
    }
}

// ---------------- KA: taps -> out_a (direct scattered) + aBTm (masked, coalesced) + chunk stats
// grid 512 = (c 0..7) x (b 0..63)
__global__ __launch_bounds__(256) void kA_stats(const float* __restrict__ dplP,
                                                const int* __restrict__ kmask,
                                                float* __restrict__ out_a,
                                                float* __restrict__ aBTm,
                                                float* __restrict__ cstat) {
    const int b = blockIdx.x & 63;
    const int c = blockIdx.x >> 6;
    const int tid = threadIdx.x;
    const int t = c * 256 + tid;
    __shared__ float red[4];

    const float* d0 = dplP + (0 * Bn + b) * DROW + DPAD;
    const float* d1 = dplP + (1 * Bn + b) * DROW + DPAD;
    const float* d2 = dplP + (2 * Bn + b) * DROW + DPAD;
    const float x0 = d0[t - 1];
    const float x2 = d2[t + 1];
    const float a = d1[t] + (t > 0 ? x0 : 0.f) + (t < Ln - 1 ? x2 : 0.f);
    const int m = kmask[t * Bn + b];
    out_a[t * Bn + b] = a;                       // direct scattered emit (full occupancy)
    aBTm[b * Ln + t] = m ? a : -1e30f;           // masked value for kB (no kmask read there)

    float lmax = m ? a : -FLT_MAX;
#pragma unroll
    for (int off = 32; off; off >>= 1) lmax = fmaxf(lmax, __shfl_xor(lmax, off));
    if ((tid & 63) == 0) red[tid >> 6] = lmax;
    __syncthreads();
    const float mxc = fmaxf(fmaxf(red[0], red[1]), fmaxf(red[2], red[3]));
    __syncthreads();
    float lsum = m ? __expf(a - mxc) : 0.f;
#pragma unroll
    for (int off = 32; off; off >>= 1) lsum += __shfl_xor(lsum, off);
    if ((tid & 63) == 0) red[tid >> 6] = lsum;
    __syncthreads();
    if (tid == 0) {
        cstat[(b * 8 + c) * 2 + 0] = mxc;
        cstat[(b * 8 + c) * 2 + 1] = red[0] + red[1] + red[2] + red[3];
    }
}

// ---------------- KB: combine stats, e -> out_e (direct), 4-deep significance-sparse PV
// grid 512 = (c 0..7) x (b 0..63)
// PV skips rows with a-mx < -30 (e < 9.4e-14; total attend error < 1e-9 << fp32 noise).
// out_e is still exact for every t.
__global__ __launch_bounds__(256) void kB_pv(const float* __restrict__ aBTm,
                                             const float* __restrict__ cstat,
                                             const float* __restrict__ v,
                                             float* __restrict__ out_e,
                                             float* __restrict__ vpart) {
    const int b = blockIdx.x & 63;
    const int c = blockIdx.x >> 6;
    const int tid = threadIdx.x;
    const int t = c * 256 + tid;

    // uniform in-register combine of the 8 chunk stats for this b
    const float* cs = cstat + b * 16;
    float mx = -FLT_MAX;
#pragma unroll
    for (int j = 0; j < 8; ++j)
        if (cs[2 * j + 1] > 0.f) mx = fmaxf(mx, cs[2 * j]);
    float sum = 0.f;
#pragma unroll
    for (int j = 0; j < 8; ++j)
        if (cs[2 * j + 1] > 0.f) sum += cs[2 * j + 1] * __expf(cs[2 * j] - mx);
    const float inv = 1.f / sum;

    const float am = aBTm[b * Ln + t];           // -1e30 where masked -> e == 0
    const float e = __expf(am - mx) * inv;
    out_e[t * Bn + b] = e;                       // direct scattered emit (exact, all t)

    const bool sig = (am - mx) > -30.f;          // significance cutoff for PV only

    __shared__ float es[256];
    __shared__ unsigned long long bm[4];
    __shared__ int lst[256];
    es[tid] = e;
    const unsigned long long bal = __ballot(sig);
    if ((tid & 63) == 0) bm[tid >> 6] = bal;
    __syncthreads();

    // wave-parallel compaction of significant indices into lst (ascending, deterministic)
    const int wv = tid >> 6;
    const int lane = tid & 63;
    int off = 0;
#pragma unroll
    for (int w = 0; w < 4; ++w)
        if (w < wv) off += __popcll(bm[w]);
    if (sig) {
        int rank = __popcll(bal & ((1ull << lane) - 1ull));
        lst[off + rank] = tid;
    }
    const int n = __popcll(bm[0]) + __popcll(bm[1]) + __popcll(bm[2]) + __popcll(bm[3]);
    __syncthreads();

    // 4-deep pipelined sparse PV
    f2 a0 = (f2)0.f, a1 = (f2)0.f, a2 = (f2)0.f, a3 = (f2)0.f;
    int i = 0;
    for (; i + 4 <= n; i += 4) {
        const int t0 = lst[i], t1 = lst[i + 1], t2 = lst[i + 2], t3 = lst[i + 3];
        const f2 v0 = __builtin_nontemporal_load((const f2*)(v + (((size_t)(c * 256 + t0) * Bn + b) << 9)) + tid);
        const f2 v1 = __builtin_nontemporal_load((const f2*)(v + (((size_t)(c * 256 + t1) * Bn + b) << 9)) + tid);
        const f2 v2 = __builtin_nontemporal_load((const f2*)(v + (((size_t)(c * 256 + t2) * Bn + b) << 9)) + tid);
        const f2 v3 = __builtin_nontemporal_load((const f2*)(v + (((size_t)(c * 256 + t3) * Bn + b) << 9)) + tid);
        a0 += es[t0] * v0;
        a1 += es[t1] * v1;
        a2 += es[t2] * v2;
        a3 += es[t3] * v3;
    }
    for (; i < n; ++i) {
        const int tt = lst[i];
        const f2 vv = __builtin_nontemporal_load((const f2*)(v + (((size_t)(c * 256 + tt) * Bn + b) << 9)) + tid);
        a0 += es[tt] * vv;
    }
    const f2 s = (a0 + a1) + (a2 + a3);
    *(f2*)&vpart[((c * Bn + b) << 9) + tid * 2] = s;
}

// ---------------- KC: reduce vpart -> attend[b, v]  (128 blocks)
__global__ __launch_bounds__(256) void kC_fin(const float* __restrict__ vpart,
                                              float* __restrict__ out_att) {
    const int idx = blockIdx.x * 256 + threadIdx.x;   // [0, 32768)
    float s = 0.f;
#pragma unroll
    for (int cc = 0; cc < 8; ++cc) s += vpart[cc * (Bn * Vn) + idx];
    out_att[idx] = s;
}

extern "C" void kernel_launch(void* const* d_in, const int* in_sizes, int n_in,
                              void* d_out, int out_size, void* d_ws, size_t ws_size,
                              hipStream_t stream) {
    const float* q = (const float*)d_in[0];
    const float* k = (const float*)d_in[1];
    const float* v = (const float*)d_in[2];
    const int* kmask = (const int*)d_in[3];
    const float* W = (const float*)d_in[4];
    const float* bias = (const float*)d_in[5];

    float* out = (float*)d_out;
    float* out_a = out;                      // [L, B]
    float* out_e = out + Ln * Bn;            // [L, B]
    float* out_att = out + 2 * Ln * Bn;      // [B, V]

    float* ws = (float*)d_ws;
    float* kern = ws + OFF_KERN;
    float* dplP = ws + OFF_DPL;
    float* aBTm = ws + OFF_ABT;
    float* cstat = ws + OFF_CST;
    float* scr = ws + OFF_SCR;   // gpart (k1 phase) then vpart (tail phase) — disjoint in time

    k1_gemm<<<dim3(24, 4), 256, 0, stream>>>(q, W, scr);
    k1b_reduce<<<(3 * Bn * Cn + 255) / 256, 256, 0, stream>>>(scr, bias, kern);
    k2_dots<<<4096, 256, 0, stream>>>(k, kern, dplP);
    kA_stats<<<512, 256, 0, stream>>>(dplP, kmask, out_a, aBTm, cstat);
    kB_pv<<<512, 256, 0, stream>>>(aBTm, cstat, v, out_e, scr);
    kC_fin<<<128, 256, 0, stream>>>(scr, out_att);
}